// Round 4
// baseline (435.694 us; speedup 1.0000x reference)
//
#include <hip/hip_runtime.h>

#define HH 320
#define WW 320
#define BB 8
static constexpr float EPS = 1e-5f;

typedef __attribute__((ext_vector_type(8))) short bf16x8;
typedef __attribute__((ext_vector_type(4))) float f32x4;

__device__ inline float bf2f(unsigned short u) {
    union { unsigned int i; float f; } v; v.i = ((unsigned int)u) << 16; return v.f;
}
__device__ inline unsigned short f2bf(float f) {
    union { float f; unsigned int i; } v; v.f = f;
    unsigned int r = v.i + 0x7fffu + ((v.i >> 16) & 1u);
    return (unsigned short)(r >> 16);
}
__device__ inline void glds16(const void* g, void* l) {
    __builtin_amdgcn_global_load_lds(
        (const __attribute__((address_space(1))) unsigned int*)g,
        (__attribute__((address_space(3))) unsigned int*)l, 16, 0, 0);
}

// ---------------- NCHW fp32 -> NHWC bf16 (CIN=32) ----------------
__global__ __launch_bounds__(256) void prep_hwc(const float* __restrict__ in,
                                                unsigned short* __restrict__ out)
{
    __shared__ float sT[32][65];
    const int tid = threadIdx.x;
    const int x0  = blockIdx.x * 64;
    const int y   = blockIdx.y;
    const int b   = blockIdx.z;
    for (int e = tid; e < 32 * 64; e += 256) {
        int c = e >> 6, x = e & 63;
        sT[c][x] = in[(((size_t)(b * 32 + c) * HH) + y) * WW + x0 + x];
    }
    __syncthreads();
    for (int e = tid; e < 64 * 32; e += 256) {
        int x = e >> 5, c = e & 31;
        out[((((size_t)b * HH + y) * WW) + x0 + x) * 32 + c] = f2bf(sT[c][x]);
    }
}

// ---------------- weights OIHW fp32 -> [kk][oc][ic] bf16 ----------------
__global__ void wprep_kernel(const float* __restrict__ w1, const float* __restrict__ w2,
                             unsigned short* __restrict__ wt1, unsigned short* __restrict__ wt2)
{
    int i = blockIdx.x * 256 + threadIdx.x;
    if (i < 9 * 64 * 32) {
        int ic = i & 31, oc = (i >> 5) & 63, kk = i >> 11;
        wt1[i] = f2bf(w1[(oc * 32 + ic) * 9 + kk]);
    }
    if (i < 9 * 64 * 64) {
        int ic = i & 63, oc = (i >> 6) & 63, kk = i >> 12;
        wt2[i] = f2bf(w2[(oc * 64 + ic) * 9 + kk]);
    }
}

// ---------------- implicit-GEMM conv 3x3 via MFMA ----------------
// Block: 256 thr = 4 waves. Tile: 8 rows x 64 px x 64 oc. Wave w owns rows 2w,2w+1.
// A staged via global_load_lds into bank-swizzled linear LDS (swizzle applied by
// permuting per-lane global source). B (weights) read per-fragment from L1/L2.
// ORIENT 0: D[px][oc], float4 stores to NCHW fp32 (conv2).
// ORIENT 1: D[oc][px] (swapped mfma operands), bf16x4 stores to NHWC bf16 (conv1).
template<int CIN, int ORIENT>
__global__ __launch_bounds__(256, 2) void conv_mfma(
    const unsigned short* __restrict__ in_hwc,   // [B][H][W][CIN] bf16
    const unsigned short* __restrict__ wt,       // [9][64][CIN] bf16
    const float* __restrict__ bias,              // [64]
    unsigned short* __restrict__ out_hwc,        // ORIENT 1
    float* __restrict__ out_nchw,                // ORIENT 0
    float2* __restrict__ partials)               // [B*200][64]
{
    __shared__ __align__(16) unsigned short sA[10 * 66 * 32];   // 42240 B, swizzled
    __shared__ float sRedS[4 * 64];
    __shared__ float sRedSS[4 * 64];

    const int tid = threadIdx.x;
    const int x0 = blockIdx.x * 64;
    const int y0 = blockIdx.y * 8;
    const int b  = blockIdx.z;
    const int w  = tid >> 6;
    const int l  = tid & 63;
    const int lm = l & 15;
    const int g  = l >> 4;

    f32x4 acc[8][4];
#pragma unroll
    for (int fx = 0; fx < 8; ++fx)
#pragma unroll
        for (int fn = 0; fn < 4; ++fn)
            acc[fx][fn] = (f32x4){0.f, 0.f, 0.f, 0.f};

    for (int icc = 0; icc < CIN / 32; ++icc) {
        __syncthreads();
        // ---- stage A chunk: rows assigned per wave; interior via global_load_lds ----
        for (int r = w; r < 10; r += 4) {
            int gy = y0 + r - 1;
            unsigned short* ldsrow = sA + r * 2112;        // 264 units * 8 shorts
            if ((unsigned)gy < HH) {
                const unsigned short* rowbase =
                    in_hwc + ((size_t)(b * HH + gy) * WW) * CIN + icc * 32;
#pragma unroll
                for (int i = 0; i < 4; ++i) {
                    int u   = 4 + i * 64 + l;              // dest unit (16B)
                    int x   = u >> 2;                      // LDS px slot 1..64
                    int icq = (u & 3) ^ ((x >> 1) & 3);    // inverse swizzle on source
                    const unsigned short* gsrc = rowbase + (size_t)(x0 + x - 1) * CIN + icq * 8;
                    glds16(gsrc, ldsrow + (size_t)(4 + i * 64) * 8);
                }
            } else {
                for (int u = l; u < 264; u += 64)
                    *(bf16x8*)(ldsrow + u * 8) = (bf16x8){0,0,0,0,0,0,0,0};
            }
        }
        // ---- halo columns (px slots 0 and 65), bounds-checked ----
        for (int e = tid; e < 80; e += 256) {
            int icq = e & 3, side = (e >> 2) & 1, r = e >> 3;
            int xs = side ? 65 : 0;
            int gy = y0 + r - 1, gx = x0 + xs - 1;
            bf16x8 v = (bf16x8){0,0,0,0,0,0,0,0};
            if ((unsigned)gy < HH && (unsigned)gx < WW)
                v = *(const bf16x8*)&in_hwc[(((size_t)(b * HH + gy) * WW) + gx) * CIN + icc * 32 + icq * 8];
            int u = (xs * 4 + icq) ^ ((xs >> 1) & 3);
            *(bf16x8*)(sA + r * 2112 + u * 8) = v;
        }
        __syncthreads();

        // ---- compute ----
        const unsigned short* wbase = wt + icc * 32;
#pragma unroll
        for (int kk = 0; kk < 9; ++kk) {
            const int ky = kk / 3, kx = kk % 3;
            bf16x8 af[8], bfr[4];
#pragma unroll
            for (int fx = 0; fx < 8; ++fx) {
                int rl = 2 * w + (fx >> 2) + ky;
                int xl = (fx & 3) * 16 + lm + kx;
                int u  = (xl * 4 + g) ^ ((xl >> 1) & 3);
                af[fx] = *(const bf16x8*)(sA + rl * 2112 + u * 8);
            }
#pragma unroll
            for (int fn = 0; fn < 4; ++fn)
                bfr[fn] = *(const bf16x8*)&wbase[(size_t)(kk * 64 + fn * 16 + lm) * CIN + g * 8];
#pragma unroll
            for (int fn = 0; fn < 4; ++fn)
#pragma unroll
                for (int fx = 0; fx < 8; ++fx)
                    acc[fx][fn] = ORIENT
                        ? __builtin_amdgcn_mfma_f32_16x16x32_bf16(bfr[fn], af[fx], acc[fx][fn], 0, 0, 0)
                        : __builtin_amdgcn_mfma_f32_16x16x32_bf16(af[fx], bfr[fn], acc[fx][fn], 0, 0, 0);
        }
    }

    if (ORIENT == 1) {
        // lane: oc = 16*fo + 4g + j, px = x0 + 16*(fp&3) + lm, row = y0 + 2w + (fp>>2)
        float4 bia4[4];
#pragma unroll
        for (int fo = 0; fo < 4; ++fo) bia4[fo] = *(const float4*)&bias[fo * 16 + g * 4];

#pragma unroll
        for (int fo = 0; fo < 4; ++fo) {
            f32x4 s = {0,0,0,0}, ss = {0,0,0,0};
#pragma unroll
            for (int fp = 0; fp < 8; ++fp)
#pragma unroll
                for (int j = 0; j < 4; ++j) {
                    float v = acc[fp][fo][j] + ((const float*)&bia4[fo])[j];
                    s[j] += v; ss[j] += v * v;
                }
#pragma unroll
            for (int m = 1; m <= 8; m <<= 1)
#pragma unroll
                for (int j = 0; j < 4; ++j) {
                    s[j]  += __shfl_xor(s[j],  m);
                    ss[j] += __shfl_xor(ss[j], m);
                }
            if (lm == 0) {
                *(f32x4*)&sRedS [w * 64 + fo * 16 + g * 4] = s;
                *(f32x4*)&sRedSS[w * 64 + fo * 16 + g * 4] = ss;
            }
        }
#pragma unroll
        for (int fp = 0; fp < 8; ++fp) {
            int row = y0 + 2 * w + (fp >> 2);
            int px  = x0 + (fp & 3) * 16 + lm;
#pragma unroll
            for (int fo = 0; fo < 4; ++fo) {
                unsigned short pk[4];
#pragma unroll
                for (int j = 0; j < 4; ++j)
                    pk[j] = f2bf(acc[fp][fo][j] + ((const float*)&bia4[fo])[j]);
                *(short4*)&out_hwc[(((size_t)b * HH + row) * WW + px) * 64 + fo * 16 + g * 4] =
                    *(short4*)pk;
            }
        }
    } else {
        // lane: oc = 16*fn + lm, px = x0 + 16*(fx&3) + 4g + j, row = y0 + 2w + (fx>>2)
        float bia[4];
#pragma unroll
        for (int fn = 0; fn < 4; ++fn) bia[fn] = bias[fn * 16 + lm];

#pragma unroll
        for (int fn = 0; fn < 4; ++fn) {
            float s = 0.f, ss = 0.f;
#pragma unroll
            for (int fx = 0; fx < 8; ++fx)
#pragma unroll
                for (int j = 0; j < 4; ++j) {
                    float v = acc[fx][fn][j] + bia[fn];
                    s += v; ss += v * v;
                }
            s  += __shfl_xor(s, 16);  s  += __shfl_xor(s, 32);
            ss += __shfl_xor(ss, 16); ss += __shfl_xor(ss, 32);
            if (l < 16) { sRedS[w * 64 + fn * 16 + l] = s; sRedSS[w * 64 + fn * 16 + l] = ss; }
        }
#pragma unroll
        for (int fx = 0; fx < 8; ++fx) {
            int row = y0 + 2 * w + (fx >> 2);
            int xb  = x0 + (fx & 3) * 16 + g * 4;
#pragma unroll
            for (int fn = 0; fn < 4; ++fn) {
                float4 v = make_float4(acc[fx][fn][0] + bia[fn], acc[fx][fn][1] + bia[fn],
                                       acc[fx][fn][2] + bia[fn], acc[fx][fn][3] + bia[fn]);
                *(float4*)&out_nchw[(((size_t)(b * 64 + fn * 16 + lm) * HH) + row) * WW + xb] = v;
            }
        }
    }

    __syncthreads();
    if (tid < 64) {
        float S = 0.f, SS = 0.f;
#pragma unroll
        for (int q = 0; q < 4; ++q) { S += sRedS[q * 64 + tid]; SS += sRedSS[q * 64 + tid]; }
        partials[(((size_t)b * 40 + blockIdx.y) * 5 + blockIdx.x) * 64 + tid] = make_float2(S, SS);
    }
}

// ---------------- partials -> (mean, rstd) ----------------
__global__ __launch_bounds__(256) void reduce_stats(const float2* __restrict__ partials,
                                                    float2* __restrict__ stats)
{
    const int b  = blockIdx.x;
    const int oc = threadIdx.x & 63;
    const int q  = threadIdx.x >> 6;
    float s = 0.f, ss = 0.f;
    for (int i = q; i < 200; i += 4) {
        float2 p = partials[((size_t)b * 200 + i) * 64 + oc];
        s += p.x; ss += p.y;
    }
    __shared__ float2 red[4][64];
    red[q][oc] = make_float2(s, ss);
    __syncthreads();
    if (threadIdx.x < 64) {
        float S = 0.f, SS = 0.f;
#pragma unroll
        for (int k = 0; k < 4; ++k) { S += red[k][threadIdx.x].x; SS += red[k][threadIdx.x].y; }
        const float n = (float)(HH * WW);
        float mean = S / n;
        float var  = fmaxf(SS / n - mean * mean, 0.f);
        stats[b * 64 + threadIdx.x] = make_float2(mean, rsqrtf(var + EPS));
    }
}

// ---------------- in-place normalize + relu on NHWC bf16 ----------------
__global__ __launch_bounds__(256) void norm_h(unsigned short* __restrict__ h,
                                              const float2* __restrict__ stats)
{
    __shared__ float2 st[64];
    const int b = blockIdx.y;
    if (threadIdx.x < 64) st[threadIdx.x] = stats[b * 64 + threadIdx.x];
    __syncthreads();
    size_t i = (size_t)blockIdx.x * 256 + threadIdx.x;   // bf16x8 chunk within b
    unsigned short* p = h + ((size_t)b * HH * WW * 64) + i * 8;
    int c0 = (int)((i & 7) * 8);
    bf16x8 v = *(bf16x8*)p;
    unsigned short res[8];
#pragma unroll
    for (int j = 0; j < 8; ++j) {
        float2 ms = st[c0 + j];
        res[j] = f2bf(fmaxf((bf2f(((unsigned short*)&v)[j]) - ms.x) * ms.y, 0.f));
    }
    *(bf16x8*)p = *(bf16x8*)res;
}

// ---------------- in-place normalize + relu on NCHW fp32 ----------------
__global__ __launch_bounds__(256) void finalize_kernel(float* __restrict__ out,
                                                       const float2* __restrict__ stats)
{
    const int bc  = blockIdx.x >> 2;
    const int seg = blockIdx.x & 3;
    float2 ms = stats[bc];
    float4* p = (float4*)(out + (size_t)bc * (HH * WW));
    const int n4 = HH * WW / 4;
    for (int i = seg * (n4 / 4) + threadIdx.x; i < (seg + 1) * (n4 / 4); i += 256) {
        float4 v = p[i];
        v.x = fmaxf((v.x - ms.x) * ms.y, 0.f);
        v.y = fmaxf((v.y - ms.x) * ms.y, 0.f);
        v.z = fmaxf((v.z - ms.x) * ms.y, 0.f);
        v.w = fmaxf((v.w - ms.x) * ms.y, 0.f);
        p[i] = v;
    }
}

extern "C" void kernel_launch(void* const* d_in, const int* in_sizes, int n_in,
                              void* d_out, int out_size, void* d_ws, size_t ws_size,
                              hipStream_t stream)
{
    const float* x  = (const float*)d_in[0];
    const float* w1 = (const float*)d_in[1];
    const float* b1 = (const float*)d_in[2];
    const float* w2 = (const float*)d_in[3];
    const float* b2 = (const float*)d_in[4];
    float* out = (float*)d_out;

    char* ws = (char*)d_ws;
    size_t off = 0;
    unsigned short* h_hwc = (unsigned short*)(ws + off); off += (size_t)BB * HH * WW * 64 * 2;
    unsigned short* x_hwc = (unsigned short*)(ws + off); off += (size_t)BB * HH * WW * 32 * 2;
    unsigned short* wt1   = (unsigned short*)(ws + off); off += 9 * 64 * 32 * 2;
    unsigned short* wt2   = (unsigned short*)(ws + off); off += 9 * 64 * 64 * 2;
    float2* partials      = (float2*)(ws + off);         off += (size_t)BB * 200 * 64 * sizeof(float2);
    float2* stats1        = (float2*)(ws + off);         off += 512 * sizeof(float2);
    float2* stats2        = (float2*)(ws + off);         off += 512 * sizeof(float2);

    dim3 cgrid(5, 40, BB);

    prep_hwc<<<dim3(5, HH, BB), 256, 0, stream>>>(x, x_hwc);
    wprep_kernel<<<144, 256, 0, stream>>>(w1, w2, wt1, wt2);

    // conv1: raw conv -> NHWC bf16 h + stats partials (swapped orientation)
    conv_mfma<32, 1><<<cgrid, 256, 0, stream>>>(x_hwc, wt1, b1, h_hwc, nullptr, partials);
    reduce_stats<<<BB, 256, 0, stream>>>(partials, stats1);
    // normalize h in place (relu((h-mu)*rstd))
    norm_h<<<dim3(3200, BB), 256, 0, stream>>>(h_hwc, stats1);
    // conv2: normalized h -> raw conv NCHW fp32 out + stats partials
    conv_mfma<64, 0><<<cgrid, 256, 0, stream>>>(h_hwc, wt2, b2, nullptr, out, partials);
    reduce_stats<<<BB, 256, 0, stream>>>(partials, stats2);
    // in-place normalize + relu on d_out
    finalize_kernel<<<BB * 64 * 4, 256, 0, stream>>>(out, stats2);
}